// Round 3
// baseline (1503.748 us; speedup 1.0000x reference)
//
#include <hip/hip_runtime.h>
#include <hip/hip_bf16.h>

// ---------------------------------------------------------------------------
// GCN: 3x (GEMM -> sym-normalized aggregation(+self-loop) -> +bias -> ReLU)
//      -> global max pool per graph -> MLP head.  All fp32.
// GEMM: 128-row tile, 256 thr, 8x8 micro-tile, ds_read_b128 both operands.
// Aggregation via CSR gather (built per call), 2-way edge unroll.
// ---------------------------------------------------------------------------

__global__ void deg_count_kernel(const int* __restrict__ ei, int* __restrict__ cnt, int E) {
    int e = blockIdx.x * 256 + threadIdx.x;
    if (e < E) atomicAdd(&cnt[ei[E + e]], 1);
}

__global__ void deg_fin_kernel(const int* __restrict__ cnt, float* __restrict__ disq, int N) {
    int i = blockIdx.x * 256 + threadIdx.x;
    if (i < N) disq[i] = rsqrtf((float)cnt[i] + 1.0f);
}

// ---- 2-level exclusive scan of cnt[N] -> rp[N] (chunk = 1024 = 256 thr x 4)
__global__ void scan_pass1(const int* __restrict__ cnt, int* __restrict__ bsum, int N) {
    __shared__ int s[256];
    int t = threadIdx.x;
    int base = blockIdx.x * 1024 + t * 4;
    int sum = 0;
    #pragma unroll
    for (int j = 0; j < 4; ++j) { int idx = base + j; if (idx < N) sum += cnt[idx]; }
    s[t] = sum; __syncthreads();
    for (int off = 128; off; off >>= 1) {
        if (t < off) s[t] += s[t + off];
        __syncthreads();
    }
    if (t == 0) bsum[blockIdx.x] = s[0];
}

__global__ void scan_pass2(const int* __restrict__ bsum, int* __restrict__ boff,
                           int nchunks, int* __restrict__ rp, int N, int E) {
    __shared__ int s[256];
    int t = threadIdx.x;
    int v = (t < nchunks) ? bsum[t] : 0;
    s[t] = v; __syncthreads();
    for (int off = 1; off < 256; off <<= 1) {
        int x = (t >= off) ? s[t - off] : 0;
        __syncthreads();
        s[t] += x;
        __syncthreads();
    }
    boff[t] = s[t] - v;           // exclusive
    if (t == 0) rp[N] = E;
}

__global__ void scan_pass3(const int* __restrict__ cnt, const int* __restrict__ boff,
                           int* __restrict__ rp, int N) {
    __shared__ int s[256];
    int t = threadIdx.x;
    int base = blockIdx.x * 1024 + t * 4;
    int v[4]; int sum = 0;
    #pragma unroll
    for (int j = 0; j < 4; ++j) { int idx = base + j; v[j] = (idx < N) ? cnt[idx] : 0; sum += v[j]; }
    s[t] = sum; __syncthreads();
    for (int off = 1; off < 256; off <<= 1) {
        int x = (t >= off) ? s[t - off] : 0;
        __syncthreads();
        s[t] += x;
        __syncthreads();
    }
    int ex = s[t] - sum + boff[blockIdx.x];
    #pragma unroll
    for (int j = 0; j < 4; ++j) { int idx = base + j; if (idx < N) { rp[idx] = ex; ex += v[j]; } }
}

__global__ void scatter_kernel(const int* __restrict__ ei, const float* __restrict__ disq,
                               const int* __restrict__ rp, int* __restrict__ fill,
                               int* __restrict__ srcs, float* __restrict__ nv, int E) {
    int e = blockIdx.x * 256 + threadIdx.x;
    if (e >= E) return;
    int s = ei[e];
    int d = ei[E + e];
    int pos = rp[d] + atomicAdd(&fill[d], 1);
    srcs[pos] = s;
    nv[pos] = disq[s] * disq[d];
}

// ---- fp32 GEMM: C[N,BN] = A[N,K] @ W[K,BN]
// BM=128, BK=16, 256 threads (16x16), each thread 8 rows x (BN/16) cols.
// A staged transposed in LDS -> both operands read as float4 (ds_read_b128).
template <int BN>
__global__ __launch_bounds__(256) void gemm_kernel(
    const float* __restrict__ A, const float* __restrict__ W,
    float* __restrict__ C, int N, int K)
{
    constexpr int BM = 128, BK = 16;
    constexpr int TN = BN / 16;            // cols per thread (8 or 4)
    __shared__ float As[BK][BM + 4];       // +4: keep 16B alignment, shift banks
    __shared__ float Ws[BK][BN + 4];
    const int tid = threadIdx.x;
    const int tr = tid >> 4;               // 0..15 -> rows tr*8..tr*8+7
    const int tc = tid & 15;               // 0..15 -> cols tc*TN..+TN-1
    const long base = (long)blockIdx.x * BM;

    float acc[8][TN];
    #pragma unroll
    for (int i = 0; i < 8; ++i)
        #pragma unroll
        for (int j = 0; j < TN; ++j) acc[i][j] = 0.f;

    for (int k0 = 0; k0 < K; k0 += BK) {
        // stage A transposed: As[k][m] = A[base+m][k0+k]
        #pragma unroll
        for (int i = tid; i < BM * BK; i += 256) {
            int r = i >> 4, k = i & 15;
            long row = base + r;
            As[k][r] = (row < N && (k0 + k) < K) ? A[row * K + k0 + k] : 0.f;
        }
        // stage W: Ws[k][n]
        #pragma unroll
        for (int i = tid; i < BK * BN; i += 256) {
            int k = i / BN, n = i % BN;
            Ws[k][n] = ((k0 + k) < K) ? W[(long)(k0 + k) * BN + n] : 0.f;
        }
        __syncthreads();
        #pragma unroll
        for (int k = 0; k < BK; ++k) {
            float4 a0 = *(const float4*)&As[k][tr * 8];
            float4 a1 = *(const float4*)&As[k][tr * 8 + 4];
            float am[8] = {a0.x, a0.y, a0.z, a0.w, a1.x, a1.y, a1.z, a1.w};
            if constexpr (TN == 8) {
                float4 w0 = *(const float4*)&Ws[k][tc * 8];
                float4 w1 = *(const float4*)&Ws[k][tc * 8 + 4];
                float wn[8] = {w0.x, w0.y, w0.z, w0.w, w1.x, w1.y, w1.z, w1.w};
                #pragma unroll
                for (int i = 0; i < 8; ++i)
                    #pragma unroll
                    for (int j = 0; j < 8; ++j) acc[i][j] += am[i] * wn[j];
            } else {
                float4 w0 = *(const float4*)&Ws[k][tc * 4];
                float wn[4] = {w0.x, w0.y, w0.z, w0.w};
                #pragma unroll
                for (int i = 0; i < 8; ++i)
                    #pragma unroll
                    for (int j = 0; j < 4; ++j) acc[i][j] += am[i] * wn[j];
            }
        }
        __syncthreads();
    }
    #pragma unroll
    for (int i = 0; i < 8; ++i) {
        long row = base + tr * 8 + i;
        if (row < N) {
            float* cp = &C[row * BN + tc * TN];
            if constexpr (TN == 8) {
                float4 v0 = {acc[i][0], acc[i][1], acc[i][2], acc[i][3]};
                float4 v1 = {acc[i][4], acc[i][5], acc[i][6], acc[i][7]};
                ((float4*)cp)[0] = v0;
                ((float4*)cp)[1] = v1;
            } else {
                float4 v0 = {acc[i][0], acc[i][1], acc[i][2], acc[i][3]};
                ((float4*)cp)[0] = v0;
            }
        }
    }
}

// ---- aggregation: h[i] = relu( sum_{e in CSR(i)} xw[src_e]*nv_e + xw[i]*disq[i]^2 + bias )
// 256-thread blocks, 4 nodes/block (one wave each), 2-way edge unroll.
template <int C>
__global__ __launch_bounds__(256) void agg_kernel(
    const float* __restrict__ xw, const float* __restrict__ disq,
    const int* __restrict__ rp, const int* __restrict__ srcs,
    const float* __restrict__ nv, const float* __restrict__ bias,
    float* __restrict__ h, int N)
{
    int i = blockIdx.x * 4 + (threadIdx.x >> 6);
    if (i >= N) return;
    int lane = threadIdx.x & 63;
    int e0 = rp[i], e1 = rp[i + 1];
    if constexpr (C == 128) {
        const float2* xw2 = (const float2*)xw;
        float2 acc0{0.f, 0.f}, acc1{0.f, 0.f};
        int e = e0;
        for (; e + 1 < e1; e += 2) {
            int s0 = srcs[e], s1 = srcs[e + 1];
            float w0 = nv[e], w1 = nv[e + 1];
            float2 v0 = xw2[(long)s0 * 64 + lane];
            float2 v1 = xw2[(long)s1 * 64 + lane];
            acc0.x += v0.x * w0; acc0.y += v0.y * w0;
            acc1.x += v1.x * w1; acc1.y += v1.y * w1;
        }
        if (e < e1) {
            int s0 = srcs[e]; float w0 = nv[e];
            float2 v0 = xw2[(long)s0 * 64 + lane];
            acc0.x += v0.x * w0; acc0.y += v0.y * w0;
        }
        float ds = disq[i];
        float wself = ds * ds;
        float2 v = xw2[(long)i * 64 + lane];
        float2 b = ((const float2*)bias)[lane];
        float ox = fmaxf(acc0.x + acc1.x + v.x * wself + b.x, 0.f);
        float oy = fmaxf(acc0.y + acc1.y + v.y * wself + b.y, 0.f);
        float2 o{ox, oy};
        ((float2*)h)[(long)i * 64 + lane] = o;
    } else {   // C == 64
        float acc0 = 0.f, acc1 = 0.f;
        int e = e0;
        for (; e + 1 < e1; e += 2) {
            int s0 = srcs[e], s1 = srcs[e + 1];
            float w0 = nv[e], w1 = nv[e + 1];
            acc0 += xw[(long)s0 * 64 + lane] * w0;
            acc1 += xw[(long)s1 * 64 + lane] * w1;
        }
        if (e < e1) acc0 += xw[(long)srcs[e] * 64 + lane] * nv[e];
        float ds = disq[i];
        float acc = acc0 + acc1 + xw[(long)i * 64 + lane] * ds * ds;
        acc = fmaxf(acc + bias[lane], 0.f);
        h[(long)i * 64 + lane] = acc;
    }
}

// ---- global max pool: g[batch[n]][c] = max over nodes (values >= 0 post-ReLU)
__global__ void pool_kernel(const float* __restrict__ h, const int* __restrict__ batch,
                            float* __restrict__ g, int N) {
    int total = N * 64;
    for (int idx = blockIdx.x * blockDim.x + threadIdx.x; idx < total;
         idx += gridDim.x * blockDim.x) {
        int node = idx >> 6;
        int c = idx & 63;
        float v = h[idx];
        int b = batch[node];
        atomicMax((int*)&g[b * 64 + c], __float_as_int(v));
    }
}

// ---- head: out[r] = relu(g[r]@Wh1+bh1) @ Wh2 + bh2
__global__ void head_kernel(const float* __restrict__ g, const float* __restrict__ Wh1,
                            const float* __restrict__ bh1, const float* __restrict__ Wh2,
                            const float* __restrict__ bh2, float* __restrict__ out, int G) {
    int r = threadIdx.x;
    if (r >= G) return;
    float hid[32];
    #pragma unroll
    for (int j = 0; j < 32; ++j) {
        float s = bh1[j];
        for (int k = 0; k < 64; ++k) s += g[r * 64 + k] * Wh1[k * 32 + j];
        hid[j] = fmaxf(s, 0.f);
    }
    float o = bh2[0];
    #pragma unroll
    for (int j = 0; j < 32; ++j) o += hid[j] * Wh2[j];
    out[r] = o;
}

extern "C" void kernel_launch(void* const* d_in, const int* in_sizes, int n_in,
                              void* d_out, int out_size, void* d_ws, size_t ws_size,
                              hipStream_t stream) {
    const float* x   = (const float*)d_in[0];
    const int*   ei  = (const int*)d_in[1];
    const int*   bat = (const int*)d_in[2];
    const float* W1  = (const float*)d_in[3];
    const float* b1  = (const float*)d_in[4];
    const float* W2  = (const float*)d_in[5];
    const float* b2  = (const float*)d_in[6];
    const float* W3  = (const float*)d_in[7];
    const float* b3  = (const float*)d_in[8];
    const float* Wh1 = (const float*)d_in[9];
    const float* bh1 = (const float*)d_in[10];
    const float* Wh2 = (const float*)d_in[11];
    const float* bh2 = (const float*)d_in[12];
    float* out = (float*)d_out;

    const int N = in_sizes[2];
    const int E = in_sizes[1] / 2;
    const int K1 = in_sizes[0] / N;   // 397
    const int G = out_size;           // 64

    // bump allocator on workspace
    char* wsp = (char*)d_ws;
    size_t off = 0;
    auto alloc = [&](size_t bytes) -> void* {
        void* p = wsp + off;
        off = (off + bytes + 255) & ~(size_t)255;
        return p;
    };
    int*   cnt  = (int*)alloc((size_t)N * 4);          // also reused as fill
    float* disq = (float*)alloc((size_t)N * 4);
    int*   rp   = (int*)alloc((size_t)(N + 1) * 4);
    int*   bsum = (int*)alloc(256 * 4);
    int*   boff = (int*)alloc(256 * 4);
    int*   srcs = (int*)alloc((size_t)E * 4);
    float* nv   = (float*)alloc((size_t)E * 4);
    float* B0   = (float*)alloc((size_t)N * 128 * 4);
    float* B1   = (float*)alloc((size_t)N * 128 * 4);
    float* g    = (float*)alloc((size_t)G * 64 * 4);

    const int nchunks = (N + 1023) / 1024;   // <= 256 assumed (98 here)

    (void)hipMemsetAsync(cnt, 0, (size_t)N * 4, stream);
    deg_count_kernel<<<(E + 255) / 256, 256, 0, stream>>>(ei, cnt, E);
    deg_fin_kernel<<<(N + 255) / 256, 256, 0, stream>>>(cnt, disq, N);
    scan_pass1<<<nchunks, 256, 0, stream>>>(cnt, bsum, N);
    scan_pass2<<<1, 256, 0, stream>>>(bsum, boff, nchunks, rp, N, E);
    scan_pass3<<<nchunks, 256, 0, stream>>>(cnt, boff, rp, N);
    (void)hipMemsetAsync(cnt, 0, (size_t)N * 4, stream);
    scatter_kernel<<<(E + 255) / 256, 256, 0, stream>>>(ei, disq, rp, cnt, srcs, nv, E);

    int gblocks = (N + 127) / 128;
    int ablocks = (N + 3) / 4;
    // layer 1
    gemm_kernel<128><<<gblocks, 256, 0, stream>>>(x, W1, B0, N, K1);
    agg_kernel<128><<<ablocks, 256, 0, stream>>>(B0, disq, rp, srcs, nv, b1, B1, N);
    // layer 2
    gemm_kernel<128><<<gblocks, 256, 0, stream>>>(B1, W2, B0, N, 128);
    agg_kernel<128><<<ablocks, 256, 0, stream>>>(B0, disq, rp, srcs, nv, b2, B1, N);
    // layer 3
    gemm_kernel<64><<<gblocks, 256, 0, stream>>>(B1, W3, B0, N, 128);
    agg_kernel<64><<<ablocks, 256, 0, stream>>>(B0, disq, rp, srcs, nv, b3, B1, N);
    // pool + head
    (void)hipMemsetAsync(g, 0, (size_t)G * 64 * 4, stream);
    pool_kernel<<<1024, 256, 0, stream>>>(B1, bat, g, N);
    head_kernel<<<1, 64, 0, stream>>>(g, Wh1, bh1, Wh2, bh2, out, G);
}

// Round 4
// 984.835 us; speedup vs baseline: 1.5269x; 1.5269x over previous
//
#include <hip/hip_runtime.h>
#include <hip/hip_bf16.h>

// ---------------------------------------------------------------------------
// GCN: 3x (GEMM -> sym-normalized aggregation(+self-loop) -> +bias -> ReLU)
//      -> global max pool per graph -> MLP head.  All fp32.
// GEMM: BM=128, BK=16, 256 thr, 8x8 micro-tile as 2x2 blocks of 4x4.
//   A transposed in LDS; all LDS reads b128, conflict-free / 2-way only.
// Aggregation via CSR gather (built per call), 2-way edge unroll.
// ---------------------------------------------------------------------------

__global__ void deg_count_kernel(const int* __restrict__ ei, int* __restrict__ cnt, int E) {
    int e = blockIdx.x * 256 + threadIdx.x;
    if (e < E) atomicAdd(&cnt[ei[E + e]], 1);
}

__global__ void deg_fin_kernel(const int* __restrict__ cnt, float* __restrict__ disq, int N) {
    int i = blockIdx.x * 256 + threadIdx.x;
    if (i < N) disq[i] = rsqrtf((float)cnt[i] + 1.0f);
}

// ---- 2-level exclusive scan of cnt[N] -> rp[N] (chunk = 1024 = 256 thr x 4)
__global__ void scan_pass1(const int* __restrict__ cnt, int* __restrict__ bsum, int N) {
    __shared__ int s[256];
    int t = threadIdx.x;
    int base = blockIdx.x * 1024 + t * 4;
    int sum = 0;
    #pragma unroll
    for (int j = 0; j < 4; ++j) { int idx = base + j; if (idx < N) sum += cnt[idx]; }
    s[t] = sum; __syncthreads();
    for (int off = 128; off; off >>= 1) {
        if (t < off) s[t] += s[t + off];
        __syncthreads();
    }
    if (t == 0) bsum[blockIdx.x] = s[0];
}

__global__ void scan_pass2(const int* __restrict__ bsum, int* __restrict__ boff,
                           int nchunks, int* __restrict__ rp, int N, int E) {
    __shared__ int s[256];
    int t = threadIdx.x;
    int v = (t < nchunks) ? bsum[t] : 0;
    s[t] = v; __syncthreads();
    for (int off = 1; off < 256; off <<= 1) {
        int x = (t >= off) ? s[t - off] : 0;
        __syncthreads();
        s[t] += x;
        __syncthreads();
    }
    boff[t] = s[t] - v;           // exclusive
    if (t == 0) rp[N] = E;
}

__global__ void scan_pass3(const int* __restrict__ cnt, const int* __restrict__ boff,
                           int* __restrict__ rp, int N) {
    __shared__ int s[256];
    int t = threadIdx.x;
    int base = blockIdx.x * 1024 + t * 4;
    int v[4]; int sum = 0;
    #pragma unroll
    for (int j = 0; j < 4; ++j) { int idx = base + j; v[j] = (idx < N) ? cnt[idx] : 0; sum += v[j]; }
    s[t] = sum; __syncthreads();
    for (int off = 1; off < 256; off <<= 1) {
        int x = (t >= off) ? s[t - off] : 0;
        __syncthreads();
        s[t] += x;
        __syncthreads();
    }
    int ex = s[t] - sum + boff[blockIdx.x];
    #pragma unroll
    for (int j = 0; j < 4; ++j) { int idx = base + j; if (idx < N) { rp[idx] = ex; ex += v[j]; } }
}

__global__ void scatter_kernel(const int* __restrict__ ei, const float* __restrict__ disq,
                               const int* __restrict__ rp, int* __restrict__ fill,
                               int* __restrict__ srcs, float* __restrict__ nv, int E) {
    int e = blockIdx.x * 256 + threadIdx.x;
    if (e >= E) return;
    int s = ei[e];
    int d = ei[E + e];
    int pos = rp[d] + atomicAdd(&fill[d], 1);
    srcs[pos] = s;
    nv[pos] = disq[s] * disq[d];
}

// ---- fp32 GEMM: C[N,BN] = A[N,K] @ W[K,BN]
// BM=128, BK=16, 256 threads (16x16). Thread (tr,tc) owns rows {tr*4..+3, 64+tr*4..+3}
// and cols {tc*4..+3, (64+tc*4..+3 if BN==128)}. All LDS reads are b128:
//   A: 4 broadcast addresses per wave (conflict-free)
//   W: stride-4-float across 16 lanes -> 2-way aliasing (free on 32 banks)
template <int BN>
__global__ __launch_bounds__(256) void gemm_kernel(
    const float* __restrict__ A, const float* __restrict__ W,
    float* __restrict__ C, int N, int K)
{
    constexpr int BM = 128, BK = 16;
    constexpr int NB = (BN == 128) ? 2 : 1;       // col blocks per thread
    __shared__ float As[BK][BM + 4];              // transposed A tile
    __shared__ float Ws[BK][BN + 4];
    const int tid = threadIdx.x;
    const int tr = tid >> 4;    // 0..15
    const int tc = tid & 15;    // 0..15
    const long base = (long)blockIdx.x * BM;
    const bool kAligned = ((K & 3) == 0);

    float acc[8][4 * NB];
    #pragma unroll
    for (int i = 0; i < 8; ++i)
        #pragma unroll
        for (int j = 0; j < 4 * NB; ++j) acc[i][j] = 0.f;

    for (int k0 = 0; k0 < K; k0 += BK) {
        // ---- stage A transposed: As[k][m] = A[base+m][k0+k]; 512 float4 chunks
        #pragma unroll
        for (int t = 0; t < 2; ++t) {
            int i = tid + t * 256;                // 0..511
            int r = i >> 2;                       // 0..127
            int kq = (i & 3) * 4;                 // 0,4,8,12
            long row = base + r;
            float f0 = 0.f, f1 = 0.f, f2 = 0.f, f3 = 0.f;
            if (row < N) {
                const float* ap = &A[row * K + k0 + kq];
                int rem = K - (k0 + kq);          // elements available
                if (rem >= 4) {
                    if (kAligned) {
                        float4 v = *(const float4*)ap;
                        f0 = v.x; f1 = v.y; f2 = v.z; f3 = v.w;
                    } else {
                        f0 = ap[0]; f1 = ap[1]; f2 = ap[2]; f3 = ap[3];
                    }
                } else {
                    if (rem > 0) f0 = ap[0];
                    if (rem > 1) f1 = ap[1];
                    if (rem > 2) f2 = ap[2];
                }
            }
            As[kq + 0][r] = f0;
            As[kq + 1][r] = f1;
            As[kq + 2][r] = f2;
            As[kq + 3][r] = f3;
        }
        // ---- stage W: Ws[k][n]; BK*BN/4 float4 chunks (W rows are 16B aligned)
        #pragma unroll
        for (int i = tid; i < BK * BN / 4; i += 256) {
            int k = i / (BN / 4);
            int nq = (i % (BN / 4)) * 4;
            float4 v = {0.f, 0.f, 0.f, 0.f};
            if (k0 + k < K) v = *(const float4*)&W[(long)(k0 + k) * BN + nq];
            *(float4*)&Ws[k][nq] = v;
        }
        __syncthreads();
        #pragma unroll
        for (int k = 0; k < BK; ++k) {
            float4 a0 = *(const float4*)&As[k][tr * 4];
            float4 a1 = *(const float4*)&As[k][64 + tr * 4];
            float am[8] = {a0.x, a0.y, a0.z, a0.w, a1.x, a1.y, a1.z, a1.w};
            float4 w0 = *(const float4*)&Ws[k][tc * 4];
            if constexpr (NB == 2) {
                float4 w1 = *(const float4*)&Ws[k][64 + tc * 4];
                float wn[8] = {w0.x, w0.y, w0.z, w0.w, w1.x, w1.y, w1.z, w1.w};
                #pragma unroll
                for (int i = 0; i < 8; ++i)
                    #pragma unroll
                    for (int j = 0; j < 8; ++j) acc[i][j] += am[i] * wn[j];
            } else {
                float wn[4] = {w0.x, w0.y, w0.z, w0.w};
                #pragma unroll
                for (int i = 0; i < 8; ++i)
                    #pragma unroll
                    for (int j = 0; j < 4; ++j) acc[i][j] += am[i] * wn[j];
            }
        }
        __syncthreads();
    }
    // ---- epilogue
    #pragma unroll
    for (int rb = 0; rb < 2; ++rb) {
        #pragma unroll
        for (int i = 0; i < 4; ++i) {
            long row = base + rb * 64 + tr * 4 + i;
            if (row < N) {
                int ai = rb * 4 + i;
                float4 v0 = {acc[ai][0], acc[ai][1], acc[ai][2], acc[ai][3]};
                *(float4*)&C[row * BN + tc * 4] = v0;
                if constexpr (NB == 2) {
                    float4 v1 = {acc[ai][4], acc[ai][5], acc[ai][6], acc[ai][7]};
                    *(float4*)&C[row * BN + 64 + tc * 4] = v1;
                }
            }
        }
    }
}

// ---- aggregation: h[i] = relu( sum_{e in CSR(i)} xw[src_e]*nv_e + xw[i]*disq[i]^2 + bias )
// 256-thread blocks, 4 nodes/block (one wave each), 2-way edge unroll.
template <int C>
__global__ __launch_bounds__(256) void agg_kernel(
    const float* __restrict__ xw, const float* __restrict__ disq,
    const int* __restrict__ rp, const int* __restrict__ srcs,
    const float* __restrict__ nv, const float* __restrict__ bias,
    float* __restrict__ h, int N)
{
    int i = blockIdx.x * 4 + (threadIdx.x >> 6);
    if (i >= N) return;
    int lane = threadIdx.x & 63;
    int e0 = rp[i], e1 = rp[i + 1];
    if constexpr (C == 128) {
        const float2* xw2 = (const float2*)xw;
        float2 acc0{0.f, 0.f}, acc1{0.f, 0.f};
        int e = e0;
        for (; e + 1 < e1; e += 2) {
            int s0 = srcs[e], s1 = srcs[e + 1];
            float w0 = nv[e], w1 = nv[e + 1];
            float2 v0 = xw2[(long)s0 * 64 + lane];
            float2 v1 = xw2[(long)s1 * 64 + lane];
            acc0.x += v0.x * w0; acc0.y += v0.y * w0;
            acc1.x += v1.x * w1; acc1.y += v1.y * w1;
        }
        if (e < e1) {
            int s0 = srcs[e]; float w0 = nv[e];
            float2 v0 = xw2[(long)s0 * 64 + lane];
            acc0.x += v0.x * w0; acc0.y += v0.y * w0;
        }
        float ds = disq[i];
        float wself = ds * ds;
        float2 v = xw2[(long)i * 64 + lane];
        float2 b = ((const float2*)bias)[lane];
        float ox = fmaxf(acc0.x + acc1.x + v.x * wself + b.x, 0.f);
        float oy = fmaxf(acc0.y + acc1.y + v.y * wself + b.y, 0.f);
        float2 o{ox, oy};
        ((float2*)h)[(long)i * 64 + lane] = o;
    } else {   // C == 64
        float acc0 = 0.f, acc1 = 0.f;
        int e = e0;
        for (; e + 1 < e1; e += 2) {
            int s0 = srcs[e], s1 = srcs[e + 1];
            float w0 = nv[e], w1 = nv[e + 1];
            acc0 += xw[(long)s0 * 64 + lane] * w0;
            acc1 += xw[(long)s1 * 64 + lane] * w1;
        }
        if (e < e1) acc0 += xw[(long)srcs[e] * 64 + lane] * nv[e];
        float ds = disq[i];
        float acc = acc0 + acc1 + xw[(long)i * 64 + lane] * ds * ds;
        acc = fmaxf(acc + bias[lane], 0.f);
        h[(long)i * 64 + lane] = acc;
    }
}

// ---- global max pool: g[batch[n]][c] = max over nodes (values >= 0 post-ReLU)
__global__ void pool_kernel(const float* __restrict__ h, const int* __restrict__ batch,
                            float* __restrict__ g, int N) {
    int total = N * 64;
    for (int idx = blockIdx.x * blockDim.x + threadIdx.x; idx < total;
         idx += gridDim.x * blockDim.x) {
        int node = idx >> 6;
        int c = idx & 63;
        float v = h[idx];
        int b = batch[node];
        atomicMax((int*)&g[b * 64 + c], __float_as_int(v));
    }
}

// ---- head: out[r] = relu(g[r]@Wh1+bh1) @ Wh2 + bh2
__global__ void head_kernel(const float* __restrict__ g, const float* __restrict__ Wh1,
                            const float* __restrict__ bh1, const float* __restrict__ Wh2,
                            const float* __restrict__ bh2, float* __restrict__ out, int G) {
    int r = threadIdx.x;
    if (r >= G) return;
    float hid[32];
    #pragma unroll
    for (int j = 0; j < 32; ++j) {
        float s = bh1[j];
        for (int k = 0; k < 64; ++k) s += g[r * 64 + k] * Wh1[k * 32 + j];
        hid[j] = fmaxf(s, 0.f);
    }
    float o = bh2[0];
    #pragma unroll
    for (int j = 0; j < 32; ++j) o += hid[j] * Wh2[j];
    out[r] = o;
}

extern "C" void kernel_launch(void* const* d_in, const int* in_sizes, int n_in,
                              void* d_out, int out_size, void* d_ws, size_t ws_size,
                              hipStream_t stream) {
    const float* x   = (const float*)d_in[0];
    const int*   ei  = (const int*)d_in[1];
    const int*   bat = (const int*)d_in[2];
    const float* W1  = (const float*)d_in[3];
    const float* b1  = (const float*)d_in[4];
    const float* W2  = (const float*)d_in[5];
    const float* b2  = (const float*)d_in[6];
    const float* W3  = (const float*)d_in[7];
    const float* b3  = (const float*)d_in[8];
    const float* Wh1 = (const float*)d_in[9];
    const float* bh1 = (const float*)d_in[10];
    const float* Wh2 = (const float*)d_in[11];
    const float* bh2 = (const float*)d_in[12];
    float* out = (float*)d_out;

    const int N = in_sizes[2];
    const int E = in_sizes[1] / 2;
    const int K1 = in_sizes[0] / N;   // 397
    const int G = out_size;           // 64

    // bump allocator on workspace
    char* wsp = (char*)d_ws;
    size_t off = 0;
    auto alloc = [&](size_t bytes) -> void* {
        void* p = wsp + off;
        off = (off + bytes + 255) & ~(size_t)255;
        return p;
    };
    int*   cnt  = (int*)alloc((size_t)N * 4);          // also reused as fill
    float* disq = (float*)alloc((size_t)N * 4);
    int*   rp   = (int*)alloc((size_t)(N + 1) * 4);
    int*   bsum = (int*)alloc(256 * 4);
    int*   boff = (int*)alloc(256 * 4);
    int*   srcs = (int*)alloc((size_t)E * 4);
    float* nv   = (float*)alloc((size_t)E * 4);
    float* B0   = (float*)alloc((size_t)N * 128 * 4);
    float* B1   = (float*)alloc((size_t)N * 128 * 4);
    float* g    = (float*)alloc((size_t)G * 64 * 4);

    const int nchunks = (N + 1023) / 1024;   // <= 256 assumed (98 here)

    (void)hipMemsetAsync(cnt, 0, (size_t)N * 4, stream);
    deg_count_kernel<<<(E + 255) / 256, 256, 0, stream>>>(ei, cnt, E);
    deg_fin_kernel<<<(N + 255) / 256, 256, 0, stream>>>(cnt, disq, N);
    scan_pass1<<<nchunks, 256, 0, stream>>>(cnt, bsum, N);
    scan_pass2<<<1, 256, 0, stream>>>(bsum, boff, nchunks, rp, N, E);
    scan_pass3<<<nchunks, 256, 0, stream>>>(cnt, boff, rp, N);
    (void)hipMemsetAsync(cnt, 0, (size_t)N * 4, stream);
    scatter_kernel<<<(E + 255) / 256, 256, 0, stream>>>(ei, disq, rp, cnt, srcs, nv, E);

    int gblocks = (N + 127) / 128;
    int ablocks = (N + 3) / 4;
    // layer 1
    gemm_kernel<128><<<gblocks, 256, 0, stream>>>(x, W1, B0, N, K1);
    agg_kernel<128><<<ablocks, 256, 0, stream>>>(B0, disq, rp, srcs, nv, b1, B1, N);
    // layer 2
    gemm_kernel<128><<<gblocks, 256, 0, stream>>>(B1, W2, B0, N, 128);
    agg_kernel<128><<<ablocks, 256, 0, stream>>>(B0, disq, rp, srcs, nv, b2, B1, N);
    // layer 3
    gemm_kernel<64><<<gblocks, 256, 0, stream>>>(B1, W3, B0, N, 128);
    agg_kernel<64><<<ablocks, 256, 0, stream>>>(B0, disq, rp, srcs, nv, b3, B1, N);
    // pool + head
    (void)hipMemsetAsync(g, 0, (size_t)G * 64 * 4, stream);
    pool_kernel<<<1024, 256, 0, stream>>>(B1, bat, g, N);
    head_kernel<<<1, 64, 0, stream>>>(g, Wh1, bh1, Wh2, bh2, out, G);
}

// Round 5
// 899.787 us; speedup vs baseline: 1.6712x; 1.0945x over previous
//
#include <hip/hip_runtime.h>
#include <hip/hip_bf16.h>

// ---------------------------------------------------------------------------
// GCN: 3x (GEMM -> sym-normalized aggregation(+self-loop) -> +bias -> ReLU)
//      -> global max pool per graph -> MLP head.  All fp32.
// GEMM: BM=64, BN=128/64, 128 thr, 8x8 micro-tile as 2x2 blocks of 4x4.
// Agg: CSR gather, float4/lane (2 edges per wave-load for C=128, 4 for C=64),
//      packed int2 (src, norm) edge records, cross-half shfl combine.
// ---------------------------------------------------------------------------

__global__ void deg_count_kernel(const int* __restrict__ ei, int* __restrict__ cnt, int E) {
    int e = blockIdx.x * 256 + threadIdx.x;
    if (e < E) atomicAdd(&cnt[ei[E + e]], 1);
}

__global__ void deg_fin_kernel(const int* __restrict__ cnt, float* __restrict__ disq, int N) {
    int i = blockIdx.x * 256 + threadIdx.x;
    if (i < N) disq[i] = rsqrtf((float)cnt[i] + 1.0f);
}

// ---- 2-level exclusive scan of cnt[N] -> rp[N] (chunk = 1024 = 256 thr x 4)
__global__ void scan_pass1(const int* __restrict__ cnt, int* __restrict__ bsum, int N) {
    __shared__ int s[256];
    int t = threadIdx.x;
    int base = blockIdx.x * 1024 + t * 4;
    int sum = 0;
    #pragma unroll
    for (int j = 0; j < 4; ++j) { int idx = base + j; if (idx < N) sum += cnt[idx]; }
    s[t] = sum; __syncthreads();
    for (int off = 128; off; off >>= 1) {
        if (t < off) s[t] += s[t + off];
        __syncthreads();
    }
    if (t == 0) bsum[blockIdx.x] = s[0];
}

__global__ void scan_pass2(const int* __restrict__ bsum, int* __restrict__ boff,
                           int nchunks, int* __restrict__ rp, int N, int E) {
    __shared__ int s[256];
    int t = threadIdx.x;
    int v = (t < nchunks) ? bsum[t] : 0;
    s[t] = v; __syncthreads();
    for (int off = 1; off < 256; off <<= 1) {
        int x = (t >= off) ? s[t - off] : 0;
        __syncthreads();
        s[t] += x;
        __syncthreads();
    }
    boff[t] = s[t] - v;           // exclusive
    if (t == 0) rp[N] = E;
}

__global__ void scan_pass3(const int* __restrict__ cnt, const int* __restrict__ boff,
                           int* __restrict__ rp, int N) {
    __shared__ int s[256];
    int t = threadIdx.x;
    int base = blockIdx.x * 1024 + t * 4;
    int v[4]; int sum = 0;
    #pragma unroll
    for (int j = 0; j < 4; ++j) { int idx = base + j; v[j] = (idx < N) ? cnt[idx] : 0; sum += v[j]; }
    s[t] = sum; __syncthreads();
    for (int off = 1; off < 256; off <<= 1) {
        int x = (t >= off) ? s[t - off] : 0;
        __syncthreads();
        s[t] += x;
        __syncthreads();
    }
    int ex = s[t] - sum + boff[blockIdx.x];
    #pragma unroll
    for (int j = 0; j < 4; ++j) { int idx = base + j; if (idx < N) { rp[idx] = ex; ex += v[j]; } }
}

__global__ void scatter_kernel(const int* __restrict__ ei, const float* __restrict__ disq,
                               const int* __restrict__ rp, int* __restrict__ fill,
                               int2* __restrict__ esw, int E) {
    int e = blockIdx.x * 256 + threadIdx.x;
    if (e >= E) return;
    int s = ei[e];
    int d = ei[E + e];
    int pos = rp[d] + atomicAdd(&fill[d], 1);
    int2 p; p.x = s; p.y = __float_as_int(disq[s] * disq[d]);
    esw[pos] = p;
}

// ---- fp32 GEMM: C[N,BN] = A[N,K] @ W[K,BN]
// BM=64, BK=16, 128 threads (8x16). Thread (tr,tc) owns rows {tr*4..+3, 32+tr*4..+3}
// and cols {tc*4..+3, (64+tc*4..+3 if BN==128)}. All LDS reads b128:
//   A: broadcast groups (conflict-free), W: stride-4-float -> 2-way (free).
template <int BN>
__global__ __launch_bounds__(128) void gemm_kernel(
    const float* __restrict__ A, const float* __restrict__ W,
    float* __restrict__ C, int N, int K)
{
    constexpr int BM = 64, BK = 16;
    constexpr int NB = (BN == 128) ? 2 : 1;       // col blocks per thread
    __shared__ float As[BK][BM + 4];              // transposed A tile
    __shared__ float Ws[BK][BN + 4];
    const int tid = threadIdx.x;
    const int tr = tid >> 4;    // 0..7
    const int tc = tid & 15;    // 0..15
    const long base = (long)blockIdx.x * BM;
    const bool kAligned = ((K & 3) == 0);

    float acc[8][4 * NB];
    #pragma unroll
    for (int i = 0; i < 8; ++i)
        #pragma unroll
        for (int j = 0; j < 4 * NB; ++j) acc[i][j] = 0.f;

    for (int k0 = 0; k0 < K; k0 += BK) {
        // ---- stage A transposed: As[k][m] = A[base+m][k0+k]; 256 float4 chunks
        #pragma unroll
        for (int t = 0; t < 2; ++t) {
            int i = tid + t * 128;                // 0..255
            int r = i >> 2;                       // 0..63
            int kq = (i & 3) * 4;                 // 0,4,8,12
            long row = base + r;
            float f0 = 0.f, f1 = 0.f, f2 = 0.f, f3 = 0.f;
            if (row < N) {
                const float* ap = &A[row * K + k0 + kq];
                int rem = K - (k0 + kq);          // elements available
                if (rem >= 4) {
                    if (kAligned) {
                        float4 v = *(const float4*)ap;
                        f0 = v.x; f1 = v.y; f2 = v.z; f3 = v.w;
                    } else {
                        f0 = ap[0]; f1 = ap[1]; f2 = ap[2]; f3 = ap[3];
                    }
                } else {
                    if (rem > 0) f0 = ap[0];
                    if (rem > 1) f1 = ap[1];
                    if (rem > 2) f2 = ap[2];
                }
            }
            As[kq + 0][r] = f0;
            As[kq + 1][r] = f1;
            As[kq + 2][r] = f2;
            As[kq + 3][r] = f3;
        }
        // ---- stage W: Ws[k][n]; BK*BN/4 float4 chunks
        #pragma unroll
        for (int i = tid; i < BK * BN / 4; i += 128) {
            int k = i / (BN / 4);
            int nq = (i % (BN / 4)) * 4;
            float4 v = {0.f, 0.f, 0.f, 0.f};
            if (k0 + k < K) v = *(const float4*)&W[(long)(k0 + k) * BN + nq];
            *(float4*)&Ws[k][nq] = v;
        }
        __syncthreads();
        #pragma unroll
        for (int k = 0; k < BK; ++k) {
            float4 a0 = *(const float4*)&As[k][tr * 4];
            float4 a1 = *(const float4*)&As[k][32 + tr * 4];
            float am[8] = {a0.x, a0.y, a0.z, a0.w, a1.x, a1.y, a1.z, a1.w};
            float4 w0 = *(const float4*)&Ws[k][tc * 4];
            if constexpr (NB == 2) {
                float4 w1 = *(const float4*)&Ws[k][64 + tc * 4];
                float wn[8] = {w0.x, w0.y, w0.z, w0.w, w1.x, w1.y, w1.z, w1.w};
                #pragma unroll
                for (int i = 0; i < 8; ++i)
                    #pragma unroll
                    for (int j = 0; j < 8; ++j) acc[i][j] += am[i] * wn[j];
            } else {
                float wn[4] = {w0.x, w0.y, w0.z, w0.w};
                #pragma unroll
                for (int i = 0; i < 8; ++i)
                    #pragma unroll
                    for (int j = 0; j < 4; ++j) acc[i][j] += am[i] * wn[j];
            }
        }
        __syncthreads();
    }
    // ---- epilogue
    #pragma unroll
    for (int rb = 0; rb < 2; ++rb) {
        #pragma unroll
        for (int i = 0; i < 4; ++i) {
            long row = base + rb * 32 + tr * 4 + i;
            if (row < N) {
                int ai = rb * 4 + i;
                float4 v0 = {acc[ai][0], acc[ai][1], acc[ai][2], acc[ai][3]};
                *(float4*)&C[row * BN + tc * 4] = v0;
                if constexpr (NB == 2) {
                    float4 v1 = {acc[ai][4], acc[ai][5], acc[ai][6], acc[ai][7]};
                    *(float4*)&C[row * BN + 64 + tc * 4] = v1;
                }
            }
        }
    }
}

// ---- aggregation: h[i] = relu( sum_e xw[src_e]*nv_e + xw[i]*disq[i]^2 + bias )
// 4 nodes/block (one wave each). float4 per lane:
//   C=128: 32 lanes cover a row; 2 edges per wave vector-load (half = lane>>5)
//   C=64 : 16 lanes cover a row; 4 edges per wave vector-load (quarter = lane>>4)
template <int C>
__global__ __launch_bounds__(256) void agg_kernel(
    const float* __restrict__ xw, const float* __restrict__ disq,
    const int* __restrict__ rp, const int2* __restrict__ esw,
    const float* __restrict__ bias, float* __restrict__ h, int N)
{
    int i = blockIdx.x * 4 + (threadIdx.x >> 6);
    if (i >= N) return;
    int lane = threadIdx.x & 63;
    int e0 = rp[i], e1 = rp[i + 1];
    const float4* xw4 = (const float4*)xw;
    constexpr int RQ = C / 4;              // float4s per row (32 or 16)
    constexpr int EPW = 64 / RQ;           // edges per wave load (2 or 4)
    int sub = lane / RQ;                   // which edge slot this lane serves
    int col = lane % RQ;                   // float4 column within row

    float4 acc0{0.f, 0.f, 0.f, 0.f}, acc1{0.f, 0.f, 0.f, 0.f};
    int e = e0 + sub;
    for (; e + EPW < e1; e += 2 * EPW) {
        int2 p0 = esw[e];
        int2 p1 = esw[e + EPW];
        float4 v0 = xw4[(long)p0.x * RQ + col];
        float4 v1 = xw4[(long)p1.x * RQ + col];
        float w0 = __int_as_float(p0.y);
        float w1 = __int_as_float(p1.y);
        acc0.x += v0.x * w0; acc0.y += v0.y * w0; acc0.z += v0.z * w0; acc0.w += v0.w * w0;
        acc1.x += v1.x * w1; acc1.y += v1.y * w1; acc1.z += v1.z * w1; acc1.w += v1.w * w1;
    }
    for (; e < e1; e += EPW) {
        int2 p0 = esw[e];
        float4 v0 = xw4[(long)p0.x * RQ + col];
        float w0 = __int_as_float(p0.y);
        acc0.x += v0.x * w0; acc0.y += v0.y * w0; acc0.z += v0.z * w0; acc0.w += v0.w * w0;
    }
    acc0.x += acc1.x; acc0.y += acc1.y; acc0.z += acc1.z; acc0.w += acc1.w;
    // combine edge-slot partials: xor-reduce over the sub dimension
    #pragma unroll
    for (int m = RQ; m < 64; m <<= 1) {
        acc0.x += __shfl_xor(acc0.x, m, 64);
        acc0.y += __shfl_xor(acc0.y, m, 64);
        acc0.z += __shfl_xor(acc0.z, m, 64);
        acc0.w += __shfl_xor(acc0.w, m, 64);
    }
    if (sub == 0) {
        float ds = disq[i];
        float ws = ds * ds;
        float4 v = xw4[(long)i * RQ + col];
        float4 b = ((const float4*)bias)[col];
        float4 o;
        o.x = fmaxf(acc0.x + v.x * ws + b.x, 0.f);
        o.y = fmaxf(acc0.y + v.y * ws + b.y, 0.f);
        o.z = fmaxf(acc0.z + v.z * ws + b.z, 0.f);
        o.w = fmaxf(acc0.w + v.w * ws + b.w, 0.f);
        ((float4*)h)[(long)i * RQ + col] = o;
    }
}

// ---- global max pool: g[batch[n]][c] = max over nodes (values >= 0 post-ReLU)
__global__ void pool_kernel(const float* __restrict__ h, const int* __restrict__ batch,
                            float* __restrict__ g, int N) {
    int total = N * 64;
    for (int idx = blockIdx.x * blockDim.x + threadIdx.x; idx < total;
         idx += gridDim.x * blockDim.x) {
        int node = idx >> 6;
        int c = idx & 63;
        float v = h[idx];
        int b = batch[node];
        atomicMax((int*)&g[b * 64 + c], __float_as_int(v));
    }
}

// ---- head: out[r] = relu(g[r]@Wh1+bh1) @ Wh2 + bh2
__global__ void head_kernel(const float* __restrict__ g, const float* __restrict__ Wh1,
                            const float* __restrict__ bh1, const float* __restrict__ Wh2,
                            const float* __restrict__ bh2, float* __restrict__ out, int G) {
    int r = threadIdx.x;
    if (r >= G) return;
    float hid[32];
    #pragma unroll
    for (int j = 0; j < 32; ++j) {
        float s = bh1[j];
        for (int k = 0; k < 64; ++k) s += g[r * 64 + k] * Wh1[k * 32 + j];
        hid[j] = fmaxf(s, 0.f);
    }
    float o = bh2[0];
    #pragma unroll
    for (int j = 0; j < 32; ++j) o += hid[j] * Wh2[j];
    out[r] = o;
}

extern "C" void kernel_launch(void* const* d_in, const int* in_sizes, int n_in,
                              void* d_out, int out_size, void* d_ws, size_t ws_size,
                              hipStream_t stream) {
    const float* x   = (const float*)d_in[0];
    const int*   ei  = (const int*)d_in[1];
    const int*   bat = (const int*)d_in[2];
    const float* W1  = (const float*)d_in[3];
    const float* b1  = (const float*)d_in[4];
    const float* W2  = (const float*)d_in[5];
    const float* b2  = (const float*)d_in[6];
    const float* W3  = (const float*)d_in[7];
    const float* b3  = (const float*)d_in[8];
    const float* Wh1 = (const float*)d_in[9];
    const float* bh1 = (const float*)d_in[10];
    const float* Wh2 = (const float*)d_in[11];
    const float* bh2 = (const float*)d_in[12];
    float* out = (float*)d_out;

    const int N = in_sizes[2];
    const int E = in_sizes[1] / 2;
    const int K1 = in_sizes[0] / N;   // 397
    const int G = out_size;           // 64

    // bump allocator on workspace
    char* wsp = (char*)d_ws;
    size_t off = 0;
    auto alloc = [&](size_t bytes) -> void* {
        void* p = wsp + off;
        off = (off + bytes + 255) & ~(size_t)255;
        return p;
    };
    int*   cnt  = (int*)alloc((size_t)N * 4);          // also reused as fill
    float* disq = (float*)alloc((size_t)N * 4);
    int*   rp   = (int*)alloc((size_t)(N + 1) * 4);
    int*   bsum = (int*)alloc(256 * 4);
    int*   boff = (int*)alloc(256 * 4);
    int2*  esw  = (int2*)alloc((size_t)E * 8);
    float* B0   = (float*)alloc((size_t)N * 128 * 4);
    float* B1   = (float*)alloc((size_t)N * 128 * 4);
    float* g    = (float*)alloc((size_t)G * 64 * 4);

    const int nchunks = (N + 1023) / 1024;   // <= 256 assumed (98 here)

    (void)hipMemsetAsync(cnt, 0, (size_t)N * 4, stream);
    deg_count_kernel<<<(E + 255) / 256, 256, 0, stream>>>(ei, cnt, E);
    deg_fin_kernel<<<(N + 255) / 256, 256, 0, stream>>>(cnt, disq, N);
    scan_pass1<<<nchunks, 256, 0, stream>>>(cnt, bsum, N);
    scan_pass2<<<1, 256, 0, stream>>>(bsum, boff, nchunks, rp, N, E);
    scan_pass3<<<nchunks, 256, 0, stream>>>(cnt, boff, rp, N);
    (void)hipMemsetAsync(cnt, 0, (size_t)N * 4, stream);
    scatter_kernel<<<(E + 255) / 256, 256, 0, stream>>>(ei, disq, rp, cnt, esw, E);

    int gblocks = (N + 63) / 64;
    int ablocks = (N + 3) / 4;
    // layer 1
    gemm_kernel<128><<<gblocks, 128, 0, stream>>>(x, W1, B0, N, K1);
    agg_kernel<128><<<ablocks, 256, 0, stream>>>(B0, disq, rp, esw, b1, B1, N);
    // layer 2
    gemm_kernel<128><<<gblocks, 128, 0, stream>>>(B1, W2, B0, N, 128);
    agg_kernel<128><<<ablocks, 256, 0, stream>>>(B0, disq, rp, esw, b2, B1, N);
    // layer 3
    gemm_kernel<64><<<gblocks, 128, 0, stream>>>(B1, W3, B0, N, 128);
    agg_kernel<64><<<ablocks, 256, 0, stream>>>(B0, disq, rp, esw, b3, B1, N);
    // pool + head
    (void)hipMemsetAsync(g, 0, (size_t)G * 64 * 4, stream);
    pool_kernel<<<1024, 256, 0, stream>>>(B1, bat, g, N);
    head_kernel<<<1, 64, 0, stream>>>(g, Wh1, bh1, Wh2, bh2, out, G);
}

// Round 6
// 809.042 us; speedup vs baseline: 1.8587x; 1.1122x over previous
//
#include <hip/hip_runtime.h>
#include <hip/hip_bf16.h>

// ---------------------------------------------------------------------------
// GCN: 3x (GEMM -> sym-normalized aggregation(+self-loop) -> +bias -> ReLU)
//      -> global max pool per graph -> MLP head.  All fp32.
// GEMM: BM=128, BK=32, 256 thr, 8x8 micro-tile (2x2 blocks of 4x4),
//   W staged via global_load_lds (width 16), A transposed manual stage.
// Agg: CSR gather, float4/lane, 4-deep unroll (8 rows in flight per wave).
// Pool: running max per block, flush on graph change (batch sorted).
// ---------------------------------------------------------------------------

__global__ void deg_count_kernel(const int* __restrict__ ei, int* __restrict__ cnt, int E) {
    int e = blockIdx.x * 256 + threadIdx.x;
    if (e < E) atomicAdd(&cnt[ei[E + e]], 1);
}

__global__ void deg_fin_kernel(const int* __restrict__ cnt, float* __restrict__ disq, int N) {
    int i = blockIdx.x * 256 + threadIdx.x;
    if (i < N) disq[i] = rsqrtf((float)cnt[i] + 1.0f);
}

// ---- 2-level exclusive scan of cnt[N] -> rp[N] (chunk = 1024 = 256 thr x 4)
__global__ void scan_pass1(const int* __restrict__ cnt, int* __restrict__ bsum, int N) {
    __shared__ int s[256];
    int t = threadIdx.x;
    int base = blockIdx.x * 1024 + t * 4;
    int sum = 0;
    #pragma unroll
    for (int j = 0; j < 4; ++j) { int idx = base + j; if (idx < N) sum += cnt[idx]; }
    s[t] = sum; __syncthreads();
    for (int off = 128; off; off >>= 1) {
        if (t < off) s[t] += s[t + off];
        __syncthreads();
    }
    if (t == 0) bsum[blockIdx.x] = s[0];
}

__global__ void scan_pass2(const int* __restrict__ bsum, int* __restrict__ boff,
                           int nchunks, int* __restrict__ rp, int N, int E) {
    __shared__ int s[256];
    int t = threadIdx.x;
    int v = (t < nchunks) ? bsum[t] : 0;
    s[t] = v; __syncthreads();
    for (int off = 1; off < 256; off <<= 1) {
        int x = (t >= off) ? s[t - off] : 0;
        __syncthreads();
        s[t] += x;
        __syncthreads();
    }
    boff[t] = s[t] - v;           // exclusive
    if (t == 0) rp[N] = E;
}

__global__ void scan_pass3(const int* __restrict__ cnt, const int* __restrict__ boff,
                           int* __restrict__ rp, int N) {
    __shared__ int s[256];
    int t = threadIdx.x;
    int base = blockIdx.x * 1024 + t * 4;
    int v[4]; int sum = 0;
    #pragma unroll
    for (int j = 0; j < 4; ++j) { int idx = base + j; v[j] = (idx < N) ? cnt[idx] : 0; sum += v[j]; }
    s[t] = sum; __syncthreads();
    for (int off = 1; off < 256; off <<= 1) {
        int x = (t >= off) ? s[t - off] : 0;
        __syncthreads();
        s[t] += x;
        __syncthreads();
    }
    int ex = s[t] - sum + boff[blockIdx.x];
    #pragma unroll
    for (int j = 0; j < 4; ++j) { int idx = base + j; if (idx < N) { rp[idx] = ex; ex += v[j]; } }
}

__global__ void scatter_kernel(const int* __restrict__ ei, const float* __restrict__ disq,
                               const int* __restrict__ rp, int* __restrict__ fill,
                               int2* __restrict__ esw, int E) {
    int e = blockIdx.x * 256 + threadIdx.x;
    if (e >= E) return;
    int s = ei[e];
    int d = ei[E + e];
    int pos = rp[d] + atomicAdd(&fill[d], 1);
    int2 p; p.x = s; p.y = __float_as_int(disq[s] * disq[d]);
    esw[pos] = p;
}

// ---- fp32 GEMM: C[N,BN] = A[N,K] @ W[K,BN]
// BM=128, BK=32, 256 threads (16x16). Thread (tr,tc) owns rows
// {tr*4..+3, 64+tr*4..+3}, cols {tc*4..+3, (64+tc*4..+3 if BN==128)}.
// A: transposed LDS, reads are 4-address broadcasts (conflict-free).
// W: staged by global_load_lds (linear LDS), reads 2-way aliasing (free).
template <int BN>
__global__ __launch_bounds__(256) void gemm_kernel(
    const float* __restrict__ A, const float* __restrict__ Wg,
    float* __restrict__ C, int N, int K)
{
    constexpr int BM = 128, BK = 32;
    constexpr int NB = (BN == 128) ? 2 : 1;       // col blocks per thread
    constexpr int CHUNKS = (BK * BN) / 256;       // 1KB chunks of W tile
    __shared__ float As[BK][BM + 4];              // transposed A tile
    __shared__ float Ws[BK][BN];                  // linear (glds target)
    const int tid = threadIdx.x;
    const int tr = tid >> 4;    // 0..15
    const int tc = tid & 15;    // 0..15
    const int wv = tid >> 6;    // wave 0..3
    const int ln = tid & 63;    // lane
    const long base = (long)blockIdx.x * BM;
    const bool kAligned = ((K & 3) == 0);

    float acc[8][4 * NB];
    #pragma unroll
    for (int i = 0; i < 8; ++i)
        #pragma unroll
        for (int j = 0; j < 4 * NB; ++j) acc[i][j] = 0.f;

    for (int k0 = 0; k0 < K; k0 += BK) {
        // ---- stage W via global_load_lds: wave-uniform LDS base + lane*16
        #pragma unroll
        for (int c = wv; c < CHUNKS; c += 4) {
            int row, coloff;
            if constexpr (BN == 128) { row = k0 + c * 2 + (ln >> 5); coloff = (ln & 31) * 4; }
            else                     { row = k0 + c * 4 + (ln >> 4); coloff = (ln & 15) * 4; }
            if (row > K - 1) row = K - 1;   // clamped rows meet zero A -> 0
            const float* gp = &Wg[(long)row * BN + coloff];
            char* lp = ((char*)&Ws[0][0]) + c * 1024;
            __builtin_amdgcn_global_load_lds(
                (const __attribute__((address_space(1))) void*)gp,
                (__attribute__((address_space(3))) void*)lp, 16, 0, 0);
        }
        // ---- stage A transposed: As[k][m] = A[base+m][k0+k]; 1024 chunks
        #pragma unroll
        for (int t = 0; t < 4; ++t) {
            int i = tid + t * 256;                // 0..1023
            int r = i >> 3;                       // 0..127
            int kq = (i & 7) * 4;                 // 0,4,...,28
            long row = base + r;
            float f0 = 0.f, f1 = 0.f, f2 = 0.f, f3 = 0.f;
            if (row < N) {
                const float* ap = &A[row * K + k0 + kq];
                int rem = K - (k0 + kq);          // elements available
                if (rem >= 4) {
                    if (kAligned) {
                        float4 v = *(const float4*)ap;
                        f0 = v.x; f1 = v.y; f2 = v.z; f3 = v.w;
                    } else {
                        f0 = ap[0]; f1 = ap[1]; f2 = ap[2]; f3 = ap[3];
                    }
                } else {
                    if (rem > 0) f0 = ap[0];
                    if (rem > 1) f1 = ap[1];
                    if (rem > 2) f2 = ap[2];
                }
            }
            As[kq + 0][r] = f0;
            As[kq + 1][r] = f1;
            As[kq + 2][r] = f2;
            As[kq + 3][r] = f3;
        }
        __syncthreads();   // drains vmcnt (glds) + lgkm (ds_writes)
        #pragma unroll
        for (int k = 0; k < BK; ++k) {
            float4 a0 = *(const float4*)&As[k][tr * 4];
            float4 a1 = *(const float4*)&As[k][64 + tr * 4];
            float am[8] = {a0.x, a0.y, a0.z, a0.w, a1.x, a1.y, a1.z, a1.w};
            float4 w0 = *(const float4*)&Ws[k][tc * 4];
            if constexpr (NB == 2) {
                float4 w1 = *(const float4*)&Ws[k][64 + tc * 4];
                float wn[8] = {w0.x, w0.y, w0.z, w0.w, w1.x, w1.y, w1.z, w1.w};
                #pragma unroll
                for (int i = 0; i < 8; ++i)
                    #pragma unroll
                    for (int j = 0; j < 8; ++j) acc[i][j] += am[i] * wn[j];
            } else {
                float wn[4] = {w0.x, w0.y, w0.z, w0.w};
                #pragma unroll
                for (int i = 0; i < 8; ++i)
                    #pragma unroll
                    for (int j = 0; j < 4; ++j) acc[i][j] += am[i] * wn[j];
            }
        }
        __syncthreads();
    }
    // ---- epilogue
    #pragma unroll
    for (int rb = 0; rb < 2; ++rb) {
        #pragma unroll
        for (int i = 0; i < 4; ++i) {
            long row = base + rb * 64 + tr * 4 + i;
            if (row < N) {
                int ai = rb * 4 + i;
                float4 v0 = {acc[ai][0], acc[ai][1], acc[ai][2], acc[ai][3]};
                *(float4*)&C[row * BN + tc * 4] = v0;
                if constexpr (NB == 2) {
                    float4 v1 = {acc[ai][4], acc[ai][5], acc[ai][6], acc[ai][7]};
                    *(float4*)&C[row * BN + 64 + tc * 4] = v1;
                }
            }
        }
    }
}

// ---- aggregation: h[i] = relu( sum_e xw[src_e]*nv_e + xw[i]*disq[i]^2 + bias )
// 4 nodes/block (one wave each). float4 per lane; EPW edges per wave-load
// (2 for C=128, 4 for C=64); 4-deep unroll -> up to 8/16 rows in flight.
template <int C>
__global__ __launch_bounds__(256) void agg_kernel(
    const float* __restrict__ xw, const float* __restrict__ disq,
    const int* __restrict__ rp, const int2* __restrict__ esw,
    const float* __restrict__ bias, float* __restrict__ h, int N)
{
    int i = blockIdx.x * 4 + (threadIdx.x >> 6);
    if (i >= N) return;
    int lane = threadIdx.x & 63;
    int e0 = rp[i], e1 = rp[i + 1];
    const float4* xw4 = (const float4*)xw;
    constexpr int RQ = C / 4;              // float4s per row (32 or 16)
    constexpr int EPW = 64 / RQ;           // edges per wave load (2 or 4)
    int sub = lane / RQ;                   // edge slot
    int col = lane % RQ;                   // float4 column within row

    float4 a0{0,0,0,0}, a1{0,0,0,0}, a2{0,0,0,0}, a3{0,0,0,0};
    int e = e0 + sub;
    for (; e + 3 * EPW < e1; e += 4 * EPW) {
        int2 p0 = esw[e];
        int2 p1 = esw[e + EPW];
        int2 p2 = esw[e + 2 * EPW];
        int2 p3 = esw[e + 3 * EPW];
        float4 v0 = xw4[(long)p0.x * RQ + col];
        float4 v1 = xw4[(long)p1.x * RQ + col];
        float4 v2 = xw4[(long)p2.x * RQ + col];
        float4 v3 = xw4[(long)p3.x * RQ + col];
        float w0 = __int_as_float(p0.y), w1 = __int_as_float(p1.y);
        float w2 = __int_as_float(p2.y), w3 = __int_as_float(p3.y);
        a0.x += v0.x * w0; a0.y += v0.y * w0; a0.z += v0.z * w0; a0.w += v0.w * w0;
        a1.x += v1.x * w1; a1.y += v1.y * w1; a1.z += v1.z * w1; a1.w += v1.w * w1;
        a2.x += v2.x * w2; a2.y += v2.y * w2; a2.z += v2.z * w2; a2.w += v2.w * w2;
        a3.x += v3.x * w3; a3.y += v3.y * w3; a3.z += v3.z * w3; a3.w += v3.w * w3;
    }
    for (; e < e1; e += EPW) {
        int2 p0 = esw[e];
        float4 v0 = xw4[(long)p0.x * RQ + col];
        float w0 = __int_as_float(p0.y);
        a0.x += v0.x * w0; a0.y += v0.y * w0; a0.z += v0.z * w0; a0.w += v0.w * w0;
    }
    a0.x += a1.x + a2.x + a3.x;
    a0.y += a1.y + a2.y + a3.y;
    a0.z += a1.z + a2.z + a3.z;
    a0.w += a1.w + a2.w + a3.w;
    // combine edge-slot partials across the sub dimension
    #pragma unroll
    for (int m = RQ; m < 64; m <<= 1) {
        a0.x += __shfl_xor(a0.x, m, 64);
        a0.y += __shfl_xor(a0.y, m, 64);
        a0.z += __shfl_xor(a0.z, m, 64);
        a0.w += __shfl_xor(a0.w, m, 64);
    }
    if (sub == 0) {
        float ds = disq[i];
        float ws = ds * ds;
        float4 v = xw4[(long)i * RQ + col];
        float4 b = ((const float4*)bias)[col];
        float4 o;
        o.x = fmaxf(a0.x + v.x * ws + b.x, 0.f);
        o.y = fmaxf(a0.y + v.y * ws + b.y, 0.f);
        o.z = fmaxf(a0.z + v.z * ws + b.z, 0.f);
        o.w = fmaxf(a0.w + v.w * ws + b.w, 0.f);
        ((float4*)h)[(long)i * RQ + col] = o;
    }
}

// ---- global max pool: batch is sorted -> per-block running max, flush on
// graph change. Block covers 512 nodes as 4 node-slots x 64 channels.
__global__ __launch_bounds__(256) void pool_kernel(
    const float* __restrict__ h, const int* __restrict__ batch,
    float* __restrict__ g, int N)
{
    int c = threadIdx.x & 63;
    int slot = threadIdx.x >> 6;
    int base = blockIdx.x * 512;
    int end = base + 512; if (end > N) end = N;
    int cur = -1; float m = 0.f;
    for (int n = base + slot; n < end; n += 4) {
        int b = batch[n];
        float v = h[(long)n * 64 + c];
        if (b != cur) {
            if (cur >= 0) atomicMax((int*)&g[cur * 64 + c], __float_as_int(m));
            cur = b; m = v;
        } else {
            m = fmaxf(m, v);
        }
    }
    if (cur >= 0) atomicMax((int*)&g[cur * 64 + c], __float_as_int(m));
}

// ---- head: out[r] = relu(g[r]@Wh1+bh1) @ Wh2 + bh2
__global__ void head_kernel(const float* __restrict__ g, const float* __restrict__ Wh1,
                            const float* __restrict__ bh1, const float* __restrict__ Wh2,
                            const float* __restrict__ bh2, float* __restrict__ out, int G) {
    int r = threadIdx.x;
    if (r >= G) return;
    float hid[32];
    #pragma unroll
    for (int j = 0; j < 32; ++j) {
        float s = bh1[j];
        for (int k = 0; k < 64; ++k) s += g[r * 64 + k] * Wh1[k * 32 + j];
        hid[j] = fmaxf(s, 0.f);
    }
    float o = bh2[0];
    #pragma unroll
    for (int j = 0; j < 32; ++j) o += hid[j] * Wh2[j];
    out[r] = o;
}

extern "C" void kernel_launch(void* const* d_in, const int* in_sizes, int n_in,
                              void* d_out, int out_size, void* d_ws, size_t ws_size,
                              hipStream_t stream) {
    const float* x   = (const float*)d_in[0];
    const int*   ei  = (const int*)d_in[1];
    const int*   bat = (const int*)d_in[2];
    const float* W1  = (const float*)d_in[3];
    const float* b1  = (const float*)d_in[4];
    const float* W2  = (const float*)d_in[5];
    const float* b2  = (const float*)d_in[6];
    const float* W3  = (const float*)d_in[7];
    const float* b3  = (const float*)d_in[8];
    const float* Wh1 = (const float*)d_in[9];
    const float* bh1 = (const float*)d_in[10];
    const float* Wh2 = (const float*)d_in[11];
    const float* bh2 = (const float*)d_in[12];
    float* out = (float*)d_out;

    const int N = in_sizes[2];
    const int E = in_sizes[1] / 2;
    const int K1 = in_sizes[0] / N;   // 397
    const int G = out_size;           // 64

    // bump allocator on workspace
    char* wsp = (char*)d_ws;
    size_t off = 0;
    auto alloc = [&](size_t bytes) -> void* {
        void* p = wsp + off;
        off = (off + bytes + 255) & ~(size_t)255;
        return p;
    };
    int*   cnt  = (int*)alloc((size_t)N * 4);          // also reused as fill
    float* disq = (float*)alloc((size_t)N * 4);
    int*   rp   = (int*)alloc((size_t)(N + 1) * 4);
    int*   bsum = (int*)alloc(256 * 4);
    int*   boff = (int*)alloc(256 * 4);
    int2*  esw  = (int2*)alloc((size_t)E * 8);
    float* B0   = (float*)alloc((size_t)N * 128 * 4);
    float* B1   = (float*)alloc((size_t)N * 128 * 4);
    float* g    = (float*)alloc((size_t)G * 64 * 4);

    const int nchunks = (N + 1023) / 1024;   // <= 256 assumed (98 here)

    (void)hipMemsetAsync(cnt, 0, (size_t)N * 4, stream);
    deg_count_kernel<<<(E + 255) / 256, 256, 0, stream>>>(ei, cnt, E);
    deg_fin_kernel<<<(N + 255) / 256, 256, 0, stream>>>(cnt, disq, N);
    scan_pass1<<<nchunks, 256, 0, stream>>>(cnt, bsum, N);
    scan_pass2<<<1, 256, 0, stream>>>(bsum, boff, nchunks, rp, N, E);
    scan_pass3<<<nchunks, 256, 0, stream>>>(cnt, boff, rp, N);
    (void)hipMemsetAsync(cnt, 0, (size_t)N * 4, stream);
    scatter_kernel<<<(E + 255) / 256, 256, 0, stream>>>(ei, disq, rp, cnt, esw, E);

    int gblocks = (N + 127) / 128;
    int ablocks = (N + 3) / 4;
    // layer 1
    gemm_kernel<128><<<gblocks, 256, 0, stream>>>(x, W1, B0, N, K1);
    agg_kernel<128><<<ablocks, 256, 0, stream>>>(B0, disq, rp, esw, b1, B1, N);
    // layer 2
    gemm_kernel<128><<<gblocks, 256, 0, stream>>>(B1, W2, B0, N, 128);
    agg_kernel<128><<<ablocks, 256, 0, stream>>>(B0, disq, rp, esw, b2, B1, N);
    // layer 3
    gemm_kernel<64><<<gblocks, 256, 0, stream>>>(B1, W3, B0, N, 128);
    agg_kernel<64><<<ablocks, 256, 0, stream>>>(B0, disq, rp, esw, b3, B1, N);
    // pool + head
    (void)hipMemsetAsync(g, 0, (size_t)G * 64 * 4, stream);
    pool_kernel<<<(N + 511) / 512, 256, 0, stream>>>(B1, bat, g, N);
    head_kernel<<<1, 64, 0, stream>>>(g, Wh1, bh1, Wh2, bh2, out, G);
}